// Round 6
// baseline (376.169 us; speedup 1.0000x reference)
//
#include <hip/hip_runtime.h>
#include <math.h>

#define BB 16
#define NN 8192
#define DD 128
#define CC 64
#define ROWS (BB*NN)            // 131072
#define INV_TEMP (1.0f/6.0f)    // temp = 2*(1+192/96) = 6
#define NEGF (-3.402823e38f)

#define RPB 128                 // rows per block (2 rows/thread x 4 c-quarters)
#define CHW 32                  // chunk width (floats of j)
#define XST 34                  // LDS row stride in dwords (2-way conflict max, 8B aligned)
#define GRIDM (ROWS / RPB)      // 1024 blocks

__device__ __forceinline__ unsigned f2bf(float f) {
    unsigned u = __builtin_bit_cast(unsigned, f);
    return (u + 0x7fffu + ((u >> 16) & 1u)) >> 16;   // RNE
}
__device__ __forceinline__ float bflo(unsigned u) { return __builtin_bit_cast(float, u << 16); }
__device__ __forceinline__ float bfhi(unsigned u) { return __builtin_bit_cast(float, u & 0xffff0000u); }

// ---------------------------------------------------------------------------
// k_main: 2 rows x 16 c per thread. Wave w = c-quarter (dict ptr wave-uniform
// -> s_load); each dict SGPR value feeds 2 fmaf (rows rloc, rloc+64), halving
// scalar-cache dict traffic vs round-4 and doubling fmaf density per js-step.
// launch_bounds(256,6): 6 blocks/CU (LDS 23.8 KB), 24 waves/CU.
// bufA is reused x-stage -> q(bf16) -> t4 exchange (strictly ordered).
// ---------------------------------------------------------------------------
__global__ __launch_bounds__(256, 6) void k_main(
    const float* __restrict__ x, const float* __restrict__ dict,
    float* __restrict__ xcg, float* __restrict__ xrg,
    unsigned* __restrict__ qg, float* __restrict__ colpart)
{
    __shared__ __align__(16) float bufA[RPB * XST];      // 17408 B
    __shared__ float red4[RPB][4];                       // 2048 B
    __shared__ float colsumA[CC];                        // 256 B
    __shared__ __align__(16) float w4s[RPB][4];          // 2048 B
    __shared__ __align__(16) int   si4s[RPB][4];         // 2048 B

    const int tid   = threadIdx.x;
    const int rloc  = tid & 63;                          // row A; row B = rloc+64
    const int qh    = tid >> 6;                          // wave id = c-quarter
    const int cbase = __builtin_amdgcn_readfirstlane(qh << 4);
    const int row0  = blockIdx.x * RPB;

    if (tid < CC) colsumA[tid] = 0.f;

    const int sr = tid >> 3;            // staging row 0..31 (+32p)
    const int sj = (tid & 7) * 4;       // staging j offset
    const float* xstage = x + (size_t)(row0 + sr) * DD + sj;

    float s[32];                        // [0..15]=row A accs, [16..31]=row B
#pragma unroll
    for (int cc = 0; cc < 32; ++cc) s[cc] = 0.f;

    // ---------------- phase 1: scores, software-pipelined staging ----------
    float4 rp[4];
#pragma unroll
    for (int p = 0; p < 4; ++p)
        rp[p] = *(const float4*)(xstage + (size_t)p * 32 * DD);
#pragma unroll
    for (int p = 0; p < 4; ++p) {
        float* dst = &bufA[XST * (sr + 32 * p) + sj];
        *(float2*)dst       = make_float2(rp[p].x, rp[p].y);
        *(float2*)(dst + 2) = make_float2(rp[p].z, rp[p].w);
    }
    __syncthreads();

    for (int ch = 0; ch < 4; ++ch) {
        const int j0 = ch * CHW;
        if (ch < 3) {   // next chunk's loads issue under compute
#pragma unroll
            for (int p = 0; p < 4; ++p)
                rp[p] = *(const float4*)(xstage + (size_t)p * 32 * DD + (j0 + CHW));
        }
        const float* xrowA = &bufA[XST * rloc];
        const float* xrowB = &bufA[XST * (rloc + 64)];
        for (int js = 0; js < CHW; js += 4) {
            const float2 a01 = *(const float2*)(xrowA + js);
            const float2 a23 = *(const float2*)(xrowA + js + 2);
            const float2 b01 = *(const float2*)(xrowB + js);
            const float2 b23 = *(const float2*)(xrowB + js + 2);
            const float* dcol = dict + (size_t)cbase * DD + (j0 + js);
#pragma unroll
            for (int cc = 0; cc < 16; ++cc) {
                const float* dp = dcol + cc * DD;   // wave-uniform -> s_load
                float aA = s[cc], aB = s[16 + cc];
                aA = fmaf(a01.x, dp[0], aA);  aB = fmaf(b01.x, dp[0], aB);
                aA = fmaf(a01.y, dp[1], aA);  aB = fmaf(b01.y, dp[1], aB);
                aA = fmaf(a23.x, dp[2], aA);  aB = fmaf(b23.x, dp[2], aB);
                aA = fmaf(a23.y, dp[3], aA);  aB = fmaf(b23.y, dp[3], aB);
                s[cc] = aA; s[16 + cc] = aB;
            }
        }
        if (ch < 3) {
            __syncthreads();   // all consumers of bufA done
#pragma unroll
            for (int p = 0; p < 4; ++p) {
                float* dst = &bufA[XST * (sr + 32 * p) + sj];
                *(float2*)dst       = make_float2(rp[p].x, rp[p].y);
                *(float2*)(dst + 2) = make_float2(rp[p].z, rp[p].w);
            }
            __syncthreads();
        }
    }

    // ---------------- phase 2: max across the 4 quarters (both rows) -------
    float lmA = s[0], lmB = s[16];
#pragma unroll
    for (int cc = 1; cc < 16; ++cc) {
        lmA = fmaxf(lmA, s[cc]);
        lmB = fmaxf(lmB, s[16 + cc]);
    }
    red4[rloc][qh]      = lmA;
    red4[rloc + 64][qh] = lmB;
    __syncthreads();
    const float mgA = fmaxf(fmaxf(red4[rloc][0], red4[rloc][1]),
                            fmaxf(red4[rloc][2], red4[rloc][3]));
    const float mgB = fmaxf(fmaxf(red4[rloc + 64][0], red4[rloc + 64][1]),
                            fmaxf(red4[rloc + 64][2], red4[rloc + 64][3]));

    // ---------------- top-4 local on RAW s (strict '>' => lowest index) ----
    float tvA[4], tvB[4]; int tiA[4], tiB[4];
#pragma unroll
    for (int t = 0; t < 4; ++t) {
        float bestA = NEGF, bestB = NEGF; int biA = 0, biB = 0;
#pragma unroll
        for (int cc = 0; cc < 16; ++cc) {
            bool usedA = false, usedB = false;
#pragma unroll
            for (int u2 = 0; u2 < 3; ++u2)
                if (u2 < t) { usedA = usedA || (cc == tiA[u2]); usedB = usedB || (cc == tiB[u2]); }
            const float vA = usedA ? NEGF : s[cc];
            const float vB = usedB ? NEGF : s[16 + cc];
            if (vA > bestA) { bestA = vA; biA = cc; }
            if (vB > bestB) { bestB = vB; biB = cc; }
        }
        tvA[t] = bestA; tiA[t] = biA;
        tvB[t] = bestB; tiB[t] = biB;
    }

    // ---------------- single exp pass: s -> e, then normalize to q ---------
    float lzA = 0.f, lzB = 0.f;
#pragma unroll
    for (int cc = 0; cc < 16; ++cc) {
        const float eA = __expf((s[cc] - mgA) * INV_TEMP);
        const float eB = __expf((s[16 + cc] - mgB) * INV_TEMP);
        s[cc] = eA; lzA += eA;
        s[16 + cc] = eB; lzB += eB;
    }
    __syncthreads();   // all mg reads done before red4 rewrite
    red4[rloc][qh]      = lzA;
    red4[rloc + 64][qh] = lzB;
    __syncthreads();
    const float rZA = 1.f / (red4[rloc][0] + red4[rloc][1] + red4[rloc][2] + red4[rloc][3]);
    const float rZB = 1.f / (red4[rloc + 64][0] + red4[rloc + 64][1] +
                             red4[rloc + 64][2] + red4[rloc + 64][3]);
#pragma unroll
    for (int cc = 0; cc < 16; ++cc) { s[cc] *= rZA; s[16 + cc] *= rZB; }

    // ---------------- q -> LDS (bf16), both rows; bufA-as-x is dead --------
    unsigned* qs = (unsigned*)bufA;
    {
        const int baseA = XST * rloc + 8 * qh;
        const int baseB = XST * (rloc + 64) + 8 * qh;
#pragma unroll
        for (int k2 = 0; k2 < 8; k2 += 2) {
            uint2 wa, wb;
            wa.x = (f2bf(s[2 * k2 + 1]) << 16) | f2bf(s[2 * k2 + 0]);
            wa.y = (f2bf(s[2 * k2 + 3]) << 16) | f2bf(s[2 * k2 + 2]);
            wb.x = (f2bf(s[16 + 2 * k2 + 1]) << 16) | f2bf(s[16 + 2 * k2 + 0]);
            wb.y = (f2bf(s[16 + 2 * k2 + 3]) << 16) | f2bf(s[16 + 2 * k2 + 2]);
            *(uint2*)&qs[baseA + k2] = wa;
            *(uint2*)&qs[baseB + k2] = wb;
        }
    }
    __syncthreads();   // q visible; s[] dead

    // ---------------- colsum partials (conflict-free reads, 8-way atomics) -
    {
        const int cp  = tid & 31;           // column pair (dword index)
        const int rr0 = (tid >> 5) * 16;    // 8 groups x 16 rows
        float c0 = 0.f, c1 = 0.f;
#pragma unroll
        for (int rr = 0; rr < 16; ++rr) {
            const unsigned u = qs[XST * (rr0 + rr) + cp];
            c0 += bflo(u); c1 += bfhi(u);
        }
        atomicAdd(&colsumA[2 * cp + 0], c0);
        atomicAdd(&colsumA[2 * cp + 1], c1);
    }

    // ---------------- q -> global (coalesced) ------------------------------
    {
        unsigned* qdst = qg + (size_t)blockIdx.x * (RPB * 32);
#pragma unroll
        for (int k4 = 0; k4 < 4; ++k4) {
            const int gd  = k4 * 1024 + tid * 4;
            const int row = gd >> 5, kk = gd & 31;
            const uint2 a = *(const uint2*)&qs[XST * row + kk];
            const uint2 b = *(const uint2*)&qs[XST * row + kk + 2];
            uint4 o; o.x = a.x; o.y = a.y; o.z = b.x; o.w = b.y;
            *(uint4*)&qdst[gd] = o;
        }
    }
    __syncthreads();   // all qs consumers done; bufA free for t4

    // ---------------- publish candidates into bufA (m-major, stride-1) -----
    {
        float* t4v = bufA;                     // [16][128] floats
        int*   t4i = (int*)(bufA + 16 * RPB);  // [16][128] ints
#pragma unroll
        for (int k = 0; k < 4; ++k) {
            t4v[(qh * 4 + k) * RPB + rloc]      = tvA[k];
            t4i[(qh * 4 + k) * RPB + rloc]      = cbase + tiA[k];
            t4v[(qh * 4 + k) * RPB + rloc + 64] = tvB[k];
            t4i[(qh * 4 + k) * RPB + rloc + 64] = cbase + tiB[k];
        }
    }
    __syncthreads();

    // ---------------- merge 16 candidates (value desc, index asc) ----------
    if (tid < RPB) {
        const float* t4v = bufA;
        const int*   t4i = (const int*)(bufA + 16 * RPB);
        float cv[16]; int ci[16];
#pragma unroll
        for (int m = 0; m < 16; ++m) {
            cv[m] = t4v[m * RPB + tid];
            ci[m] = t4i[m * RPB + tid];
        }
        float sv[4]; int si[4];
#pragma unroll
        for (int t = 0; t < 4; ++t) {
            float best = NEGF; int bi = 1 << 30;
#pragma unroll
            for (int m = 0; m < 16; ++m) {
                bool used = false;
#pragma unroll
                for (int u2 = 0; u2 < 3; ++u2)
                    if (u2 < t) used = used || (ci[m] == si[u2]);
                const bool better = !used &&
                    (cv[m] > best || (cv[m] == best && ci[m] < bi));
                best = better ? cv[m] : best;
                bi   = better ? ci[m] : bi;
            }
            sv[t] = best; si[t] = bi;
        }
        const float e1 = __expf((sv[1] - sv[0]) * INV_TEMP);
        const float e2 = __expf((sv[2] - sv[0]) * INV_TEMP);
        const float e3 = __expf((sv[3] - sv[0]) * INV_TEMP);
        const float rZ4 = 1.f / (1.f + e1 + e2 + e3);
        *(float4*)&w4s[tid][0] = make_float4(rZ4, e1 * rZ4, e2 * rZ4, e3 * rZ4);
        *(int4*)&si4s[tid][0]  = make_int4(si[0], si[1], si[2], si[3]);
    }
    __syncthreads();   // w4s/si4s visible; colsumA atomics done
    if (tid < CC) colpart[blockIdx.x * CC + tid] = colsumA[tid];

    // ---------------- phase 3: barrier-free streaming epilogue -------------
#pragma unroll 2
    for (int it = 0; it < 16; ++it) {
        const int gd  = it * 1024 + tid * 4;
        const int row = gd >> 7;
        const int dd  = gd & 127;
        const float4 wv = *(const float4*)&w4s[row][0];
        const int4  iv  = *(const int4*)&si4s[row][0];
        const size_t go = (size_t)(row0 + row) * DD + dd;
        const float4 xv = *(const float4*)(x + go);
        const float4 d0 = *(const float4*)(dict + (size_t)iv.x * DD + dd);
        const float4 d1 = *(const float4*)(dict + (size_t)iv.y * DD + dd);
        const float4 d2 = *(const float4*)(dict + (size_t)iv.z * DD + dd);
        const float4 d3 = *(const float4*)(dict + (size_t)iv.w * DD + dd);
        float4 c4, r4;
        c4.x = fmaf(wv.w, d3.x, fmaf(wv.z, d2.x, fmaf(wv.y, d1.x, wv.x * d0.x)));
        c4.y = fmaf(wv.w, d3.y, fmaf(wv.z, d2.y, fmaf(wv.y, d1.y, wv.x * d0.y)));
        c4.z = fmaf(wv.w, d3.z, fmaf(wv.z, d2.z, fmaf(wv.y, d1.z, wv.x * d0.z)));
        c4.w = fmaf(wv.w, d3.w, fmaf(wv.z, d2.w, fmaf(wv.y, d1.w, wv.x * d0.w)));
        r4.x = xv.x - c4.x; r4.y = xv.y - c4.y;
        r4.z = xv.z - c4.z; r4.w = xv.w - c4.w;
        *(float4*)(xcg + go) = c4;
        *(float4*)(xrg + go) = r4;
    }
}

// ---------------------------------------------------------------------------
// k_tail: blocks 0..15 reduce colpart[1024][64] -> colsum[64];
//         blocks 16..31 compute the ortho gram term (dict L2-resident).
// ---------------------------------------------------------------------------
__global__ __launch_bounds__(256) void k_tail(
    const float* __restrict__ colpart, float* __restrict__ colsum,
    const float* __restrict__ dict, float* __restrict__ oacc)
{
    const int tid = threadIdx.x;
    if (blockIdx.x < 16) {
        const int c   = tid & 63;
        const int seg = blockIdx.x * 4 + (tid >> 6);   // 0..63
        float v = 0.f;
#pragma unroll 8
        for (int b = 0; b < 16; ++b)
            v += colpart[(size_t)((seg * 16 + b) * 64 + c)];
        atomicAdd(&colsum[c], v);
    } else {
        const int e = (blockIdx.x - 16) * 256 + tid;   // [0,4096)
        const int i = e >> 6, jj = e & 63;
        const float* di = dict + (size_t)i * DD;
        const float* dj = dict + (size_t)jj * DD;
        float g = 0.f;
#pragma unroll 8
        for (int d = 0; d < DD; d += 4) {
            const float4 a = *(const float4*)(di + d);
            const float4 b = *(const float4*)(dj + d);
            g += a.x * b.x + a.y * b.y + a.z * b.z + a.w * b.w;
        }
        const float diff = g - ((i == jj) ? 1.f : 0.f);
        float v = diff * diff;
#pragma unroll
        for (int off = 32; off > 0; off >>= 1)
            v += __shfl_down(v, off, 64);
        if ((tid & 63) == 0) atomicAdd(oacc, v);
    }
}

// ---------------------------------------------------------------------------
// k_kl: per-row KL from bf16 q; LAST block (arrive counter) writes aux.
// ---------------------------------------------------------------------------
__global__ __launch_bounds__(256, 2) void k_kl(
    const unsigned* __restrict__ qg, const float* __restrict__ colsum,
    float* __restrict__ klacc, const float* __restrict__ oacc,
    unsigned* __restrict__ cnt, float* __restrict__ aux)
{
    __shared__ __align__(8) unsigned qs[256 * XST];  // 34816 B
    __shared__ float rF[CC], lF[CC];
    __shared__ float kred[4];
    const int tid = threadIdx.x;
    if (tid < CC) { const float F = colsum[tid]; rF[tid] = 1.f / F; lF[tid] = __logf(F); }
    const unsigned* qb = qg + (size_t)blockIdx.x * 8192;
#pragma unroll
    for (int g = 0; g < 8; ++g) {
        const int gd = g * 1024 + tid * 4;
        const uint4 v = *(const uint4*)(qb + gd);
        const int row = gd >> 5, kk = gd & 31;
        *(uint2*)&qs[XST * row + kk]     = make_uint2(v.x, v.y);
        *(uint2*)&qs[XST * row + kk + 2] = make_uint2(v.z, v.w);
    }
    __syncthreads();
    const unsigned* qr = &qs[XST * tid];
    unsigned u[32];
#pragma unroll
    for (int k = 0; k < 32; k += 2) {
        const uint2 t2 = *(const uint2*)&qr[k];
        u[k] = t2.x; u[k + 1] = t2.y;
    }
    float S = 0.f;
#pragma unroll
    for (int k = 0; k < 32; ++k) {
        const float f0 = bflo(u[k]), f1 = bfhi(u[k]);
        S = fmaf(f0 * f0, rF[2 * k], S);
        S = fmaf(f1 * f1, rF[2 * k + 1], S);
    }
    const float rS = 1.f / S;
    const float lS = __logf(S);
    float acc = 0.f;
#pragma unroll
    for (int k = 0; k < 32; ++k) {
        const float f0 = bflo(u[k]), f1 = bfhi(u[k]);
        const float p0 = f0 * f0 * rF[2 * k] * rS;
        const float p1 = f1 * f1 * rF[2 * k + 1] * rS;
        acc += p0 * (__logf(f0) - lF[2 * k] - lS);
        acc += p1 * (__logf(f1) - lF[2 * k + 1] - lS);
    }
#pragma unroll
    for (int off = 32; off > 0; off >>= 1) acc += __shfl_down(acc, off, 64);
    if ((tid & 63) == 0) kred[tid >> 6] = acc;
    __syncthreads();
    if (tid == 0) {
        atomicAdd(klacc, kred[0] + kred[1] + kred[2] + kred[3]);
        const unsigned prev = __hip_atomic_fetch_add(
            cnt, 1u, __ATOMIC_ACQ_REL, __HIP_MEMORY_SCOPE_AGENT);
        if (prev == (unsigned)(ROWS / 256 - 1)) {
            const float kt = __hip_atomic_load(klacc,
                __ATOMIC_RELAXED, __HIP_MEMORY_SCOPE_AGENT);
            const float ot = __hip_atomic_load((float*)oacc,
                __ATOMIC_RELAXED, __HIP_MEMORY_SCOPE_AGENT);
            aux[0] = 0.5f * (kt / (float)ROWS) + 0.1f * (ot / 4096.f);
        }
    }
}

// ---------------------------------------------------------------------------
extern "C" void kernel_launch(void* const* d_in, const int* in_sizes, int n_in,
                              void* d_out, int out_size, void* d_ws, size_t ws_size,
                              hipStream_t stream)
{
    const float* x    = (const float*)d_in[0];   // (16, 8192, 128)
    const float* dict = (const float*)d_in[1];   // (64, 128)
    float* out = (float*)d_out;
    float* xcg = out;                               // (B,N,D)
    float* xrg = out + (size_t)ROWS * DD;           // (B,N,D)
    float* aux = out + 2 * (size_t)ROWS * DD;       // scalar

    float* ws       = (float*)d_ws;
    float* colsum   = ws;                 // 64 floats
    float* klacc    = ws + 64;            // 1
    float* oacc     = ws + 65;            // 1
    unsigned* cnt   = (unsigned*)(ws + 66);
    float* colpart  = ws + 256;                       // 1024*64 floats = 256 KB
    unsigned* qbuf  = (unsigned*)(ws + 256 + GRIDM * CC);  // 16.75 MB

    hipMemsetAsync(d_ws, 0, 1024, stream);   // zeros colsum/klacc/oacc/cnt

    k_main<<<GRIDM,      256, 0, stream>>>(x, dict, xcg, xrg, qbuf, colpart);
    k_tail<<<32,         256, 0, stream>>>(colpart, colsum, dict, oacc);
    k_kl  <<<ROWS / 256, 256, 0, stream>>>(qbuf, colsum, klacc, oacc, cnt, aux);
}

// Round 7
// 363.270 us; speedup vs baseline: 1.0355x; 1.0355x over previous
//
#include <hip/hip_runtime.h>
#include <math.h>

#define BB 16
#define NN 8192
#define DD 128
#define CC 64
#define ROWS (BB*NN)            // 131072
#define INV_TEMP (1.0f/6.0f)    // temp = 2*(1+192/96) = 6
#define NEGF (-3.402823e38f)

#define RPB 128                 // rows per block (2 rows/thread x 4 c-quarters)
#define CHW 32                  // chunk width (floats of j)
#define XST 34                  // LDS row stride in dwords (2-way conflict max, 8B aligned)
#define GRIDM (ROWS / RPB)      // 1024 blocks

__device__ __forceinline__ unsigned f2bf(float f) {
    unsigned u = __builtin_bit_cast(unsigned, f);
    return (u + 0x7fffu + ((u >> 16) & 1u)) >> 16;   // RNE
}
__device__ __forceinline__ float bflo(unsigned u) { return __builtin_bit_cast(float, u << 16); }
__device__ __forceinline__ float bfhi(unsigned u) { return __builtin_bit_cast(float, u & 0xffff0000u); }

// ---------------------------------------------------------------------------
// k_main: 2 rows x 16 c per thread. Wave w = c-quarter (dict ptr wave-uniform
// -> s_load); each dict SGPR value feeds 2 fmaf (rows rloc, rloc+64) -> 8
// fmaf-instr per s_load_dwordx4 (2x rounds 1/4).
// __launch_bounds__(256,4): VGPR budget 128 (~90 needed, NO SPILL).
// NOTE: (256,6) forces the 64-VGPR occupancy cliff (waves/EU steps 8@<=64,
// 4@<=128) -> allocator clamped to 40 VGPR and spilled ~1KB/thread (round-6:
// FETCH +122MB, WRITE +252MB, 219us). Only (256,4) and (256,8) are safe.
// bufA is reused x-stage -> q(bf16) -> t4 exchange (strictly ordered).
// ---------------------------------------------------------------------------
__global__ __launch_bounds__(256, 4) void k_main(
    const float* __restrict__ x, const float* __restrict__ dict,
    float* __restrict__ xcg, float* __restrict__ xrg,
    unsigned* __restrict__ qg, float* __restrict__ colpart)
{
    __shared__ __align__(16) float bufA[RPB * XST];      // 17408 B
    __shared__ float red4[RPB][4];                       // 2048 B
    __shared__ float colsumA[CC];                        // 256 B
    __shared__ __align__(16) float w4s[RPB][4];          // 2048 B
    __shared__ __align__(16) int   si4s[RPB][4];         // 2048 B

    const int tid   = threadIdx.x;
    const int rloc  = tid & 63;                          // row A; row B = rloc+64
    const int qh    = tid >> 6;                          // wave id = c-quarter
    const int cbase = __builtin_amdgcn_readfirstlane(qh << 4);
    const int row0  = blockIdx.x * RPB;

    if (tid < CC) colsumA[tid] = 0.f;

    const int sr = tid >> 3;            // staging row 0..31 (+32p)
    const int sj = (tid & 7) * 4;       // staging j offset
    const float* xstage = x + (size_t)(row0 + sr) * DD + sj;

    float s[32];                        // [0..15]=row A accs, [16..31]=row B
#pragma unroll
    for (int cc = 0; cc < 32; ++cc) s[cc] = 0.f;

    // ---------------- phase 1: scores, software-pipelined staging ----------
    float4 rp[4];
#pragma unroll
    for (int p = 0; p < 4; ++p)
        rp[p] = *(const float4*)(xstage + (size_t)p * 32 * DD);
#pragma unroll
    for (int p = 0; p < 4; ++p) {
        float* dst = &bufA[XST * (sr + 32 * p) + sj];
        *(float2*)dst       = make_float2(rp[p].x, rp[p].y);
        *(float2*)(dst + 2) = make_float2(rp[p].z, rp[p].w);
    }
    __syncthreads();

    for (int ch = 0; ch < 4; ++ch) {
        const int j0 = ch * CHW;
        if (ch < 3) {   // next chunk's loads issue under compute
#pragma unroll
            for (int p = 0; p < 4; ++p)
                rp[p] = *(const float4*)(xstage + (size_t)p * 32 * DD + (j0 + CHW));
        }
        const float* xrowA = &bufA[XST * rloc];
        const float* xrowB = &bufA[XST * (rloc + 64)];
        for (int js = 0; js < CHW; js += 4) {
            const float2 a01 = *(const float2*)(xrowA + js);
            const float2 a23 = *(const float2*)(xrowA + js + 2);
            const float2 b01 = *(const float2*)(xrowB + js);
            const float2 b23 = *(const float2*)(xrowB + js + 2);
            const float* dcol = dict + (size_t)cbase * DD + (j0 + js);
#pragma unroll
            for (int cc = 0; cc < 16; ++cc) {
                const float* dp = dcol + cc * DD;   // wave-uniform -> s_load
                float aA = s[cc], aB = s[16 + cc];
                aA = fmaf(a01.x, dp[0], aA);  aB = fmaf(b01.x, dp[0], aB);
                aA = fmaf(a01.y, dp[1], aA);  aB = fmaf(b01.y, dp[1], aB);
                aA = fmaf(a23.x, dp[2], aA);  aB = fmaf(b23.x, dp[2], aB);
                aA = fmaf(a23.y, dp[3], aA);  aB = fmaf(b23.y, dp[3], aB);
                s[cc] = aA; s[16 + cc] = aB;
            }
        }
        if (ch < 3) {
            __syncthreads();   // all consumers of bufA done
#pragma unroll
            for (int p = 0; p < 4; ++p) {
                float* dst = &bufA[XST * (sr + 32 * p) + sj];
                *(float2*)dst       = make_float2(rp[p].x, rp[p].y);
                *(float2*)(dst + 2) = make_float2(rp[p].z, rp[p].w);
            }
            __syncthreads();
        }
    }

    // ---------------- phase 2: max across the 4 quarters (both rows) -------
    float lmA = s[0], lmB = s[16];
#pragma unroll
    for (int cc = 1; cc < 16; ++cc) {
        lmA = fmaxf(lmA, s[cc]);
        lmB = fmaxf(lmB, s[16 + cc]);
    }
    red4[rloc][qh]      = lmA;
    red4[rloc + 64][qh] = lmB;
    __syncthreads();
    const float mgA = fmaxf(fmaxf(red4[rloc][0], red4[rloc][1]),
                            fmaxf(red4[rloc][2], red4[rloc][3]));
    const float mgB = fmaxf(fmaxf(red4[rloc + 64][0], red4[rloc + 64][1]),
                            fmaxf(red4[rloc + 64][2], red4[rloc + 64][3]));

    // ---------------- top-4 local on RAW s (strict '>' => lowest index) ----
    float tvA[4], tvB[4]; int tiA[4], tiB[4];
#pragma unroll
    for (int t = 0; t < 4; ++t) {
        float bestA = NEGF, bestB = NEGF; int biA = 0, biB = 0;
#pragma unroll
        for (int cc = 0; cc < 16; ++cc) {
            bool usedA = false, usedB = false;
#pragma unroll
            for (int u2 = 0; u2 < 3; ++u2)
                if (u2 < t) { usedA = usedA || (cc == tiA[u2]); usedB = usedB || (cc == tiB[u2]); }
            const float vA = usedA ? NEGF : s[cc];
            const float vB = usedB ? NEGF : s[16 + cc];
            if (vA > bestA) { bestA = vA; biA = cc; }
            if (vB > bestB) { bestB = vB; biB = cc; }
        }
        tvA[t] = bestA; tiA[t] = biA;
        tvB[t] = bestB; tiB[t] = biB;
    }

    // ---------------- single exp pass: s -> e, then normalize to q ---------
    float lzA = 0.f, lzB = 0.f;
#pragma unroll
    for (int cc = 0; cc < 16; ++cc) {
        const float eA = __expf((s[cc] - mgA) * INV_TEMP);
        const float eB = __expf((s[16 + cc] - mgB) * INV_TEMP);
        s[cc] = eA; lzA += eA;
        s[16 + cc] = eB; lzB += eB;
    }
    __syncthreads();   // all mg reads done before red4 rewrite
    red4[rloc][qh]      = lzA;
    red4[rloc + 64][qh] = lzB;
    __syncthreads();
    const float rZA = 1.f / (red4[rloc][0] + red4[rloc][1] + red4[rloc][2] + red4[rloc][3]);
    const float rZB = 1.f / (red4[rloc + 64][0] + red4[rloc + 64][1] +
                             red4[rloc + 64][2] + red4[rloc + 64][3]);
#pragma unroll
    for (int cc = 0; cc < 16; ++cc) { s[cc] *= rZA; s[16 + cc] *= rZB; }

    // ---------------- q -> LDS (bf16), both rows; bufA-as-x is dead --------
    unsigned* qs = (unsigned*)bufA;
    {
        const int baseA = XST * rloc + 8 * qh;
        const int baseB = XST * (rloc + 64) + 8 * qh;
#pragma unroll
        for (int k2 = 0; k2 < 8; k2 += 2) {
            uint2 wa, wb;
            wa.x = (f2bf(s[2 * k2 + 1]) << 16) | f2bf(s[2 * k2 + 0]);
            wa.y = (f2bf(s[2 * k2 + 3]) << 16) | f2bf(s[2 * k2 + 2]);
            wb.x = (f2bf(s[16 + 2 * k2 + 1]) << 16) | f2bf(s[16 + 2 * k2 + 0]);
            wb.y = (f2bf(s[16 + 2 * k2 + 3]) << 16) | f2bf(s[16 + 2 * k2 + 2]);
            *(uint2*)&qs[baseA + k2] = wa;
            *(uint2*)&qs[baseB + k2] = wb;
        }
    }
    __syncthreads();   // q visible; s[] dead

    // ---------------- colsum partials (conflict-free reads, 8-way atomics) -
    {
        const int cp  = tid & 31;           // column pair (dword index)
        const int rr0 = (tid >> 5) * 16;    // 8 groups x 16 rows
        float c0 = 0.f, c1 = 0.f;
#pragma unroll
        for (int rr = 0; rr < 16; ++rr) {
            const unsigned u = qs[XST * (rr0 + rr) + cp];
            c0 += bflo(u); c1 += bfhi(u);
        }
        atomicAdd(&colsumA[2 * cp + 0], c0);
        atomicAdd(&colsumA[2 * cp + 1], c1);
    }

    // ---------------- q -> global (coalesced) ------------------------------
    {
        unsigned* qdst = qg + (size_t)blockIdx.x * (RPB * 32);
#pragma unroll
        for (int k4 = 0; k4 < 4; ++k4) {
            const int gd  = k4 * 1024 + tid * 4;
            const int row = gd >> 5, kk = gd & 31;
            const uint2 a = *(const uint2*)&qs[XST * row + kk];
            const uint2 b = *(const uint2*)&qs[XST * row + kk + 2];
            uint4 o; o.x = a.x; o.y = a.y; o.z = b.x; o.w = b.y;
            *(uint4*)&qdst[gd] = o;
        }
    }
    __syncthreads();   // all qs consumers done; bufA free for t4

    // ---------------- publish candidates into bufA (m-major, stride-1) -----
    {
        float* t4v = bufA;                     // [16][128] floats
        int*   t4i = (int*)(bufA + 16 * RPB);  // [16][128] ints
#pragma unroll
        for (int k = 0; k < 4; ++k) {
            t4v[(qh * 4 + k) * RPB + rloc]      = tvA[k];
            t4i[(qh * 4 + k) * RPB + rloc]      = cbase + tiA[k];
            t4v[(qh * 4 + k) * RPB + rloc + 64] = tvB[k];
            t4i[(qh * 4 + k) * RPB + rloc + 64] = cbase + tiB[k];
        }
    }
    __syncthreads();

    // ---------------- merge 16 candidates (value desc, index asc) ----------
    if (tid < RPB) {
        const float* t4v = bufA;
        const int*   t4i = (const int*)(bufA + 16 * RPB);
        float cv[16]; int ci[16];
#pragma unroll
        for (int m = 0; m < 16; ++m) {
            cv[m] = t4v[m * RPB + tid];
            ci[m] = t4i[m * RPB + tid];
        }
        float sv[4]; int si[4];
#pragma unroll
        for (int t = 0; t < 4; ++t) {
            float best = NEGF; int bi = 1 << 30;
#pragma unroll
            for (int m = 0; m < 16; ++m) {
                bool used = false;
#pragma unroll
                for (int u2 = 0; u2 < 3; ++u2)
                    if (u2 < t) used = used || (ci[m] == si[u2]);
                const bool better = !used &&
                    (cv[m] > best || (cv[m] == best && ci[m] < bi));
                best = better ? cv[m] : best;
                bi   = better ? ci[m] : bi;
            }
            sv[t] = best; si[t] = bi;
        }
        const float e1 = __expf((sv[1] - sv[0]) * INV_TEMP);
        const float e2 = __expf((sv[2] - sv[0]) * INV_TEMP);
        const float e3 = __expf((sv[3] - sv[0]) * INV_TEMP);
        const float rZ4 = 1.f / (1.f + e1 + e2 + e3);
        *(float4*)&w4s[tid][0] = make_float4(rZ4, e1 * rZ4, e2 * rZ4, e3 * rZ4);
        *(int4*)&si4s[tid][0]  = make_int4(si[0], si[1], si[2], si[3]);
    }
    __syncthreads();   // w4s/si4s visible; colsumA atomics done
    if (tid < CC) colpart[blockIdx.x * CC + tid] = colsumA[tid];

    // ---------------- phase 3: barrier-free streaming epilogue -------------
#pragma unroll 2
    for (int it = 0; it < 16; ++it) {
        const int gd  = it * 1024 + tid * 4;
        const int row = gd >> 7;
        const int dd  = gd & 127;
        const float4 wv = *(const float4*)&w4s[row][0];
        const int4  iv  = *(const int4*)&si4s[row][0];
        const size_t go = (size_t)(row0 + row) * DD + dd;
        const float4 xv = *(const float4*)(x + go);
        const float4 d0 = *(const float4*)(dict + (size_t)iv.x * DD + dd);
        const float4 d1 = *(const float4*)(dict + (size_t)iv.y * DD + dd);
        const float4 d2 = *(const float4*)(dict + (size_t)iv.z * DD + dd);
        const float4 d3 = *(const float4*)(dict + (size_t)iv.w * DD + dd);
        float4 c4, r4;
        c4.x = fmaf(wv.w, d3.x, fmaf(wv.z, d2.x, fmaf(wv.y, d1.x, wv.x * d0.x)));
        c4.y = fmaf(wv.w, d3.y, fmaf(wv.z, d2.y, fmaf(wv.y, d1.y, wv.x * d0.y)));
        c4.z = fmaf(wv.w, d3.z, fmaf(wv.z, d2.z, fmaf(wv.y, d1.z, wv.x * d0.z)));
        c4.w = fmaf(wv.w, d3.w, fmaf(wv.z, d2.w, fmaf(wv.y, d1.w, wv.x * d0.w)));
        r4.x = xv.x - c4.x; r4.y = xv.y - c4.y;
        r4.z = xv.z - c4.z; r4.w = xv.w - c4.w;
        *(float4*)(xcg + go) = c4;
        *(float4*)(xrg + go) = r4;
    }
}

// ---------------------------------------------------------------------------
// k_tail: blocks 0..15 reduce colpart[1024][64] -> colsum[64];
//         blocks 16..31 compute the ortho gram term (dict L2-resident).
// ---------------------------------------------------------------------------
__global__ __launch_bounds__(256) void k_tail(
    const float* __restrict__ colpart, float* __restrict__ colsum,
    const float* __restrict__ dict, float* __restrict__ oacc)
{
    const int tid = threadIdx.x;
    if (blockIdx.x < 16) {
        const int c   = tid & 63;
        const int seg = blockIdx.x * 4 + (tid >> 6);   // 0..63
        float v = 0.f;
#pragma unroll 8
        for (int b = 0; b < 16; ++b)
            v += colpart[(size_t)((seg * 16 + b) * 64 + c)];
        atomicAdd(&colsum[c], v);
    } else {
        const int e = (blockIdx.x - 16) * 256 + tid;   // [0,4096)
        const int i = e >> 6, jj = e & 63;
        const float* di = dict + (size_t)i * DD;
        const float* dj = dict + (size_t)jj * DD;
        float g = 0.f;
#pragma unroll 8
        for (int d = 0; d < DD; d += 4) {
            const float4 a = *(const float4*)(di + d);
            const float4 b = *(const float4*)(dj + d);
            g += a.x * b.x + a.y * b.y + a.z * b.z + a.w * b.w;
        }
        const float diff = g - ((i == jj) ? 1.f : 0.f);
        float v = diff * diff;
#pragma unroll
        for (int off = 32; off > 0; off >>= 1)
            v += __shfl_down(v, off, 64);
        if ((tid & 63) == 0) atomicAdd(oacc, v);
    }
}

// ---------------------------------------------------------------------------
// k_kl: per-row KL from bf16 q; LAST block (arrive counter) writes aux.
// ---------------------------------------------------------------------------
__global__ __launch_bounds__(256, 2) void k_kl(
    const unsigned* __restrict__ qg, const float* __restrict__ colsum,
    float* __restrict__ klacc, const float* __restrict__ oacc,
    unsigned* __restrict__ cnt, float* __restrict__ aux)
{
    __shared__ __align__(8) unsigned qs[256 * XST];  // 34816 B
    __shared__ float rF[CC], lF[CC];
    __shared__ float kred[4];
    const int tid = threadIdx.x;
    if (tid < CC) { const float F = colsum[tid]; rF[tid] = 1.f / F; lF[tid] = __logf(F); }
    const unsigned* qb = qg + (size_t)blockIdx.x * 8192;
#pragma unroll
    for (int g = 0; g < 8; ++g) {
        const int gd = g * 1024 + tid * 4;
        const uint4 v = *(const uint4*)(qb + gd);
        const int row = gd >> 5, kk = gd & 31;
        *(uint2*)&qs[XST * row + kk]     = make_uint2(v.x, v.y);
        *(uint2*)&qs[XST * row + kk + 2] = make_uint2(v.z, v.w);
    }
    __syncthreads();
    const unsigned* qr = &qs[XST * tid];
    unsigned u[32];
#pragma unroll
    for (int k = 0; k < 32; k += 2) {
        const uint2 t2 = *(const uint2*)&qr[k];
        u[k] = t2.x; u[k + 1] = t2.y;
    }
    float S = 0.f;
#pragma unroll
    for (int k = 0; k < 32; ++k) {
        const float f0 = bflo(u[k]), f1 = bfhi(u[k]);
        S = fmaf(f0 * f0, rF[2 * k], S);
        S = fmaf(f1 * f1, rF[2 * k + 1], S);
    }
    const float rS = 1.f / S;
    const float lS = __logf(S);
    float acc = 0.f;
#pragma unroll
    for (int k = 0; k < 32; ++k) {
        const float f0 = bflo(u[k]), f1 = bfhi(u[k]);
        const float p0 = f0 * f0 * rF[2 * k] * rS;
        const float p1 = f1 * f1 * rF[2 * k + 1] * rS;
        acc += p0 * (__logf(f0) - lF[2 * k] - lS);
        acc += p1 * (__logf(f1) - lF[2 * k + 1] - lS);
    }
#pragma unroll
    for (int off = 32; off > 0; off >>= 1) acc += __shfl_down(acc, off, 64);
    if ((tid & 63) == 0) kred[tid >> 6] = acc;
    __syncthreads();
    if (tid == 0) {
        atomicAdd(klacc, kred[0] + kred[1] + kred[2] + kred[3]);
        const unsigned prev = __hip_atomic_fetch_add(
            cnt, 1u, __ATOMIC_ACQ_REL, __HIP_MEMORY_SCOPE_AGENT);
        if (prev == (unsigned)(ROWS / 256 - 1)) {
            const float kt = __hip_atomic_load(klacc,
                __ATOMIC_RELAXED, __HIP_MEMORY_SCOPE_AGENT);
            const float ot = __hip_atomic_load((float*)oacc,
                __ATOMIC_RELAXED, __HIP_MEMORY_SCOPE_AGENT);
            aux[0] = 0.5f * (kt / (float)ROWS) + 0.1f * (ot / 4096.f);
        }
    }
}

// ---------------------------------------------------------------------------
extern "C" void kernel_launch(void* const* d_in, const int* in_sizes, int n_in,
                              void* d_out, int out_size, void* d_ws, size_t ws_size,
                              hipStream_t stream)
{
    const float* x    = (const float*)d_in[0];   // (16, 8192, 128)
    const float* dict = (const float*)d_in[1];   // (64, 128)
    float* out = (float*)d_out;
    float* xcg = out;                               // (B,N,D)
    float* xrg = out + (size_t)ROWS * DD;           // (B,N,D)
    float* aux = out + 2 * (size_t)ROWS * DD;       // scalar

    float* ws       = (float*)d_ws;
    float* colsum   = ws;                 // 64 floats
    float* klacc    = ws + 64;            // 1
    float* oacc     = ws + 65;            // 1
    unsigned* cnt   = (unsigned*)(ws + 66);
    float* colpart  = ws + 256;                       // 1024*64 floats = 256 KB
    unsigned* qbuf  = (unsigned*)(ws + 256 + GRIDM * CC);  // 16.75 MB

    hipMemsetAsync(d_ws, 0, 1024, stream);   // zeros colsum/klacc/oacc/cnt

    k_main<<<GRIDM,      256, 0, stream>>>(x, dict, xcg, xrg, qbuf, colpart);
    k_tail<<<32,         256, 0, stream>>>(colpart, colsum, dict, oacc);
    k_kl  <<<ROWS / 256, 256, 0, stream>>>(qbuf, colsum, klacc, oacc, cnt, aux);
}